// Round 4
// baseline (145.313 us; speedup 1.0000x reference)
//
#include <hip/hip_runtime.h>

// AbsolutePositionEncoding: out[b][s][e] = E[s>>3][e]
//   b in [0,64), s in [0,2048), e in [0,256), ALL FP32.
//   d_in[0] = x (unused), d_in[1] = E (512x256 fp32).
//
// ROUND-4 PROBE: last untested T-A cell = fill-like occupancy x NT x
// sequential runs. Evidence: rounds 0/2/3 (131k one-shot waves; 8k waves
// 2MiB-hop NT; 2k waves 64KiB seq runs) ALL give dur ~133 -> kernel portion
// ~48 us (2.8 TB/s) is structure-invariant. The rocclr fill sustains 6.5 TB/s
// at ~10% occupancy (~3 waves/CU); every variant of ours ran >=8 waves/CU.
// This kernel: 256 blocks x 256 thr = 1 block/CU, 4 waves/CU, 1024 waves,
// each wave owns a CONTIGUOUS 128 KiB run (16 objects x [1 wave-uniform
// L2-hot E-row load + 8 sequential 1 KiB NT stores]).
// PREDICTION: T-A true -> kernel ~22-26 us, dur ~107-112. dur ~130-136 ->
// all controllable knobs exhausted (4 structures invariant) -> T-B (kernel
// already at write roofline + fixed harness gap) / T-C (poison-fill MALL
// writeback drain shares HBM with any following kernel) -> declare ceiling.

typedef float floatx4 __attribute__((ext_vector_type(4)));

constexpr unsigned BATCH         = 64;
constexpr unsigned SEQ           = 2048;
constexpr unsigned EDIM          = 256;
constexpr unsigned VEC_PER_ROW   = EDIM / 4;                  // 64 float4 per row
constexpr unsigned TOTAL_VEC     = BATCH * SEQ * VEC_PER_ROW; // 8,388,608
constexpr unsigned BLOCK         = 256;                       // 4 waves
constexpr unsigned GRID          = 256;                       // 1 block/CU, 1024 waves
constexpr unsigned NWAVES        = GRID * (BLOCK / 64);       // 1024
constexpr unsigned WAVE_VEC      = TOTAL_VEC / NWAVES;        // 8192 float4 = 128 KiB run
constexpr unsigned ROWS_PER_WAVE = WAVE_VEC / VEC_PER_ROW;    // 128 seq-rows
constexpr unsigned OBJS_PER_WAVE = ROWS_PER_WAVE / 8;         // 16 objects

static_assert(WAVE_VEC * NWAVES == TOTAL_VEC, "exact cover");
static_assert((SEQ * VEC_PER_ROW) % WAVE_VEC == 0, "no plane crossing");

__global__ __launch_bounds__(BLOCK)
void ape_broadcast_kernel(const floatx4* __restrict__ E, floatx4* __restrict__ out) {
    unsigned lane = threadIdx.x & 63;
    unsigned wave = blockIdx.x * (BLOCK / 64) + (threadIdx.x >> 6);  // < 1024
    unsigned base = wave * WAVE_VEC;              // float4 index of run start
    unsigned s0   = (base >> 6) & (SEQ - 1);      // multiple of 128
    unsigned obj0 = s0 >> 3;                      // 16-aligned

    floatx4* p = out + base + lane;               // lane-interleaved, 1 KiB/wave/step
#pragma unroll
    for (unsigned oj = 0; oj < OBJS_PER_WAVE; ++oj) {
        // Wave-uniform row: 64 lanes read one 1 KiB E row (E = 512 KiB, L2-hot;
        // loads are independent of stores -> compiler prefetches across oj).
        floatx4 val = E[(obj0 + oj) * VEC_PER_ROW + lane];
#pragma unroll
        for (unsigned r = 0; r < 8; ++r) {        // 8 seq-rows share this object
            __builtin_nontemporal_store(val, p);  // no-allocate streaming store
            p += VEC_PER_ROW;                     // sequential 1 KiB steps
        }
    }
}

extern "C" void kernel_launch(void* const* d_in, const int* in_sizes, int n_in,
                              void* d_out, int out_size, void* d_ws, size_t ws_size,
                              hipStream_t stream) {
    const floatx4* E = (const floatx4*)d_in[1];   // documented dict order
    floatx4* out     = (floatx4*)d_out;
    ape_broadcast_kernel<<<GRID, BLOCK, 0, stream>>>(E, out);
}

// Round 5
// 132.436 us; speedup vs baseline: 1.0972x; 1.0972x over previous
//
#include <hip/hip_runtime.h>
#include <hip/hip_bf16.h>

// AbsolutePositionEncoding: out[b][s][e] = E[s>>3][e]
//   b in [0,64), s in [0,2048), e in [0,256), ALL FP32.
//   d_in[0] = x (64x2048 fp32, unused), d_in[1] = E (512x256 fp32).
//
// FINAL (revert-to-best after 4-round structure sweep). Session forensics:
// dur_us = harness poison-fill (537 MB, ~85 us, always the top-5 dispatches)
// + drain/launch overlap + our kernel (~21 us write floor for 134 MB).
// Kernel-structure sweep was dur-invariant:
//   131k 1-shot waves (132.8) | 8k waves x16 NT hop-stores (140.5)
//   2k waves 64KiB seq runs (133.5) | 1k waves 128KiB seq runs NT (145.3)
// -> wave count, run length, NT, load amortization all non-levers; the
// controllable term is at its floor; residual ~25 us over the 105-109 us
// traffic arithmetic (671 MB @ 6.4 TB/s) is harness-side. Keep the simplest,
// fastest form: one coalesced float4 store per thread, E rows L2-hot.

constexpr unsigned BATCH       = 64;
constexpr unsigned SEQ         = 2048;
constexpr unsigned EDIM        = 256;
constexpr unsigned VEC_PER_ROW = EDIM / 4;                   // 64 float4 per (b,s) row
constexpr unsigned TOTAL_VEC   = BATCH * SEQ * VEC_PER_ROW;  // 8,388,608 float4 stores

__global__ __launch_bounds__(256)
void ape_broadcast_kernel(const float4* __restrict__ E, float4* __restrict__ out) {
    // One float4 store per thread; consecutive lanes -> consecutive 16B chunks
    // -> 1 KiB/wave coalesced stores.
    unsigned v   = blockIdx.x * blockDim.x + threadIdx.x;  // < 8.4M, fits u32
    unsigned e4  = v & (VEC_PER_ROW - 1);   // which 4-elem group within the row
    unsigned row = v >> 6;                  // flat (b*SEQ + s)
    unsigned s   = row & (SEQ - 1);
    unsigned obj = s >> 3;                  // token -> object index (s / 8)
    out[v] = E[obj * VEC_PER_ROW + e4];     // E rows are L2-hot (512 KB total)
}

extern "C" void kernel_launch(void* const* d_in, const int* in_sizes, int n_in,
                              void* d_out, int out_size, void* d_ws, size_t ws_size,
                              hipStream_t stream) {
    // Documented dict order: d_in[0] = x (unused), d_in[1] = E_absolute_position.
    const float4* E = (const float4*)d_in[1];
    float4* out     = (float4*)d_out;

    constexpr unsigned BLOCK = 256;
    constexpr unsigned GRID  = TOTAL_VEC / BLOCK;  // 32768 blocks
    ape_broadcast_kernel<<<GRID, BLOCK, 0, stream>>>(E, out);
}